// Round 1
// baseline (465.549 us; speedup 1.0000x reference)
//
#include <hip/hip_runtime.h>

// out[f, i] = dot(kernel[f], x[i]) + dot(enc[i % P], x[i])
// x: [M=372000, K=125] f32, enc: [P=23250, 125] f32, w: [125, 64] f32 (k-major),
// out flat: [F=64, M] f32 (reference reshape is a pure reinterpret).
//
// Strategy: bf16 MFMA (16x16x32) for the kernel term (swapped product D[f][i]
// so stores are contiguous in i), exact fp32 VALU for the enc term (dominant
// magnitude) computed during LDS staging. Memory-bound: ~293 MB HBM floor.

#define N_B   16
#define P_    23250
#define K_    125
#define F_    64
#define M_TOT (N_B * P_)   // 372000
#define BM    64           // rows per block
#define KP    128          // padded K
#define LDROW 256          // bytes per LDS row (128 bf16)

typedef __bf16 bf16x8 __attribute__((ext_vector_type(8)));
typedef float  f32x4  __attribute__((ext_vector_type(4)));

__global__ __launch_bounds__(256, 4)
void eegconv_kernel(const float* __restrict__ x,
                    const float* __restrict__ enc,
                    const float* __restrict__ w,
                    float* __restrict__ out)
{
    __shared__ __bf16 xt[BM * KP];   // XOR-swizzled bf16 x tile
    __shared__ float  srow[BM];      // per-row enc.x dot

    const int tid  = threadIdx.x;
    const int lane = tid & 63;
    const int wv   = tid >> 6;          // wave 0..3 -> f range [16w, 16w+16)
    const int fl   = lane & 15;
    const int kg   = lane >> 4;         // 0..3
    const int r0   = blockIdx.x * BM;

    // ---- A fragments: kernel[f][k] = w[k*64 + f], k padded to 128 with 0 ----
    bf16x8 afrag[4];
    {
        const int f = wv * 16 + fl;
        #pragma unroll
        for (int ks = 0; ks < 4; ++ks) {
            #pragma unroll
            for (int j = 0; j < 8; ++j) {
                const int k = ks * 32 + kg * 8 + j;
                const float v = (k < K_) ? w[k * F_ + f] : 0.0f;
                afrag[ks][j] = (__bf16)v;
            }
        }
    }

    // ---- Stage x tile (bf16, swizzled) + compute srow = dot(enc_row, x_row) ----
    {
        const int row = tid >> 2;       // 0..63 (4 threads per row)
        const int t4  = tid & 3;
        const int gi  = r0 + row;
        const bool rv = gi < M_TOT;
        const float* xr = x   + (size_t)gi * K_;
        const float* er = enc + (size_t)(rv ? (gi % P_) : 0) * K_;
        float part = 0.0f;
        #pragma unroll
        for (int u = 0; u < 32; ++u) {
            const int col = u * 4 + t4;          // covers 0..127
            float xv = 0.0f;
            if (col < K_ && rv) {
                xv = xr[col];
                part += er[col] * xv;            // exact fp32 for the big term
            }
            int byte = row * LDROW + col * 2;
            byte ^= (row & 7) << 4;              // bank-conflict swizzle
            *(__bf16*)((char*)xt + byte) = (__bf16)xv;
        }
        // reduce the 4 partials of this row (lanes differ only in low 2 bits)
        part += __shfl_xor(part, 1);
        part += __shfl_xor(part, 2);
        if (t4 == 0) srow[row] = part;
    }
    __syncthreads();

    // ---- MFMA: D[f (16/wave)][i (64)] over k = 0..127 ----
    f32x4 acc[4] = { {0,0,0,0}, {0,0,0,0}, {0,0,0,0}, {0,0,0,0} };
    #pragma unroll
    for (int ks = 0; ks < 4; ++ks) {
        #pragma unroll
        for (int t = 0; t < 4; ++t) {
            const int il = t * 16 + fl;          // i within tile = B col
            int byte = il * LDROW + (ks * 32 + kg * 8) * 2;
            byte ^= (il & 7) << 4;
            const bf16x8 bfrag = *(const bf16x8*)((const char*)xt + byte);
            acc[t] = __builtin_amdgcn_mfma_f32_16x16x32_bf16(afrag[ks], bfrag, acc[t], 0, 0, 0);
        }
    }

    // ---- Epilogue: out[f*M + i] = acc + srow[i] (contiguous in i per 16 lanes) ----
    #pragma unroll
    for (int t = 0; t < 4; ++t) {
        const int il = t * 16 + fl;
        const int gi = r0 + il;
        if (gi < M_TOT) {
            const float sv = srow[il];
            #pragma unroll
            for (int j = 0; j < 4; ++j) {
                const int fg = wv * 16 + kg * 4 + j;   // C row = (lane>>4)*4 + reg
                out[(size_t)fg * M_TOT + gi] = acc[t][j] + sv;
            }
        }
    }
}

extern "C" void kernel_launch(void* const* d_in, const int* in_sizes, int n_in,
                              void* d_out, int out_size, void* d_ws, size_t ws_size,
                              hipStream_t stream)
{
    const float* x   = (const float*)d_in[0];
    const float* enc = (const float*)d_in[1];
    const float* w   = (const float*)d_in[2];
    float* out = (float*)d_out;
    const int grid = (M_TOT + BM - 1) / BM;   // 5813 blocks of 256 threads
    eegconv_kernel<<<grid, 256, 0, stream>>>(x, enc, w, out);
}

// Round 2
// 353.894 us; speedup vs baseline: 1.3155x; 1.3155x over previous
//
#include <hip/hip_runtime.h>

// out[f, i] = dot(kernel[f], x[i]) + dot(enc[i % P], x[i])
// x: [M=372000, K=125] f32, enc: [P=23250, 125] f32, w: [125, 64] f32 (k-major),
// out flat: [F=64, M] f32 (reference reshape is a pure reinterpret).
//
// Round 2: vectorized straight-line staging (f32x4, no per-element guards),
// BM=128, swapped MFMA product D[i][f] so stores are dwordx4, w-fragments
// precomputed into d_ws by a prep kernel. Memory-bound target ~47us floor.

#define P_    23250u
#define K_    125
#define F_    64
#define M_TOT 372000
#define BM    128
#define LDROW 256                      // bytes per LDS row (128 bf16)
#define NBLK  ((M_TOT + BM - 1) / BM)  // 2907

typedef __bf16 bf16;
typedef __bf16 bf16x4 __attribute__((ext_vector_type(4)));
typedef __bf16 bf16x8 __attribute__((ext_vector_type(8)));
typedef float  f32x4  __attribute__((ext_vector_type(4)));
typedef float  f32x4u __attribute__((ext_vector_type(4), aligned(4)));  // 4B-aligned vec load

// ---- prep: per-(lane,wave) kernel fragments, linear in d_ws ----------------
// thread tid -> f = (tid>>6)*16 + (tid&15), kg = (tid>>4)&3
// layout: wfrag[tid*32 + ks*8 + j] = bf16(w[(ks*32+kg*8+j)*64 + f]), 0-pad k>=125
__global__ __launch_bounds__(256, 1)
void prep_wfrag(const float* __restrict__ w, bf16* __restrict__ wfrag)
{
    const int tid = threadIdx.x;
    const int f  = ((tid >> 6) << 4) | (tid & 15);
    const int kg = (tid >> 4) & 3;
    #pragma unroll
    for (int ks = 0; ks < 4; ++ks) {
        bf16x8 fr;
        #pragma unroll
        for (int j = 0; j < 8; ++j) {
            const int k = ks * 32 + kg * 8 + j;
            fr[j] = (bf16)((k < K_) ? w[k * F_ + f] : 0.0f);
        }
        *(bf16x8*)(wfrag + tid * 32 + ks * 8) = fr;
    }
}

template<bool USE_WS>
__global__ __launch_bounds__(256, 4)
void eegconv_kernel(const float* __restrict__ x,
                    const float* __restrict__ enc,
                    const float* __restrict__ w,
                    const bf16* __restrict__ wfrag,
                    float* __restrict__ out)
{
    __shared__ bf16  xt[BM * 128];   // XOR-swizzled bf16 x tile (32 KB)
    __shared__ float srow[BM];       // per-row enc.x dot

    const int tid  = threadIdx.x;
    const int lane = tid & 63;
    const int wv   = tid >> 6;       // wave -> f-tile [16wv, 16wv+16)
    const int fl   = lane & 15;
    const int kg   = lane >> 4;      // 0..3
    const int r0   = blockIdx.x * BM;

    // ---- B operand: kernel fragments (L2-hot broadcast) ----
    bf16x8 kf[4];
    if (USE_WS) {
        const bf16x8* wf = (const bf16x8*)(wfrag + tid * 32);
        #pragma unroll
        for (int ks = 0; ks < 4; ++ks) kf[ks] = wf[ks];
    } else {
        const int f = wv * 16 + fl;
        #pragma unroll
        for (int ks = 0; ks < 4; ++ks)
            #pragma unroll
            for (int j = 0; j < 8; ++j) {
                const int k = ks * 32 + kg * 8 + j;
                kf[ks][j] = (bf16)((k < K_) ? w[k * F_ + f] : 0.0f);
            }
    }

    // ---- Stage x tile (bf16, swizzled) + srow = dot(enc_row, x_row) ----
    {
        const int row = tid >> 1;           // 2 threads per row
        const int t2  = tid & 1;
        int gi = r0 + row;
        const bool rv = gi < M_TOT;
        if (!rv) gi = 0;                    // redirect invalid rows (stores guarded later)
        const float* xr = x   + (size_t)gi * K_;
        const float* er = enc + (size_t)((unsigned)gi % P_) * K_;
        char* lbase = (char*)xt + row * LDROW;
        const int sw = (row & 7) << 4;
        float part = 0.0f;

        #pragma unroll
        for (int u = 0; u < 15; ++u) {      // c = 0..29, all full float4s
            const int c = u * 2 + t2;
            const f32x4 xv = (f32x4)*(const f32x4u*)(xr + c * 4);
            const f32x4 ev = (f32x4)*(const f32x4u*)(er + c * 4);
            part += ev.x * xv.x + ev.y * xv.y + ev.z * xv.z + ev.w * xv.w;
            bf16x4 bv;
            bv[0] = (bf16)xv.x; bv[1] = (bf16)xv.y; bv[2] = (bf16)xv.z; bv[3] = (bf16)xv.w;
            *(bf16x4*)(lbase + ((c * 8) ^ sw)) = bv;
        }
        // tail: c = 30 (full) for t2=0, c = 31 (col 124 only) for t2=1
        {
            const int c = 30 + t2;
            f32x4 xv, ev;
            if (t2 == 0) {
                xv = (f32x4)*(const f32x4u*)(xr + 120);
                ev = (f32x4)*(const f32x4u*)(er + 120);
            } else {
                xv = f32x4{xr[124], 0.f, 0.f, 0.f};
                ev = f32x4{er[124], 0.f, 0.f, 0.f};
            }
            part += ev.x * xv.x + ev.y * xv.y + ev.z * xv.z + ev.w * xv.w;
            bf16x4 bv;
            bv[0] = (bf16)xv.x; bv[1] = (bf16)xv.y; bv[2] = (bf16)xv.z; bv[3] = (bf16)xv.w;
            *(bf16x4*)(lbase + ((c * 8) ^ sw)) = bv;
        }
        part += __shfl_xor(part, 1);        // lanes (2r, 2r+1) share a row
        if (t2 == 0) srow[row] = part;
    }
    __syncthreads();

    // ---- MFMA: D[i][f], A = x rows (from LDS), B = kernel frags ----
    f32x4 acc[8];
    #pragma unroll
    for (int t = 0; t < 8; ++t) acc[t] = f32x4{0.f, 0.f, 0.f, 0.f};

    #pragma unroll
    for (int t = 0; t < 8; ++t) {
        const int il = t * 16 + fl;
        const char* rbase = (const char*)xt + il * LDROW;
        const int sw = (il & 7) << 4;
        #pragma unroll
        for (int ks = 0; ks < 4; ++ks) {
            const bf16x8 av = *(const bf16x8*)(rbase + ((ks * 64 + kg * 16) ^ sw));
            acc[t] = __builtin_amdgcn_mfma_f32_16x16x32_bf16(av, kf[ks], acc[t], 0, 0, 0);
        }
    }

    // ---- Epilogue: lane's 4 regs = 4 consecutive i -> dwordx4 stores ----
    const size_t fM = (size_t)(wv * 16 + fl) * (size_t)M_TOT;
    #pragma unroll
    for (int t = 0; t < 8; ++t) {
        const int ib = t * 16 + kg * 4;     // i within block (mult of 4)
        const int i0 = r0 + ib;
        if (i0 < M_TOT) {                   // M_TOT % 4 == 0 -> all-or-nothing
            const f32x4 sv = *(const f32x4*)&srow[ib];
            f32x4 v;
            v.x = acc[t][0] + sv.x;
            v.y = acc[t][1] + sv.y;
            v.z = acc[t][2] + sv.z;
            v.w = acc[t][3] + sv.w;
            *(f32x4*)(out + fM + i0) = v;
        }
    }
}

extern "C" void kernel_launch(void* const* d_in, const int* in_sizes, int n_in,
                              void* d_out, int out_size, void* d_ws, size_t ws_size,
                              hipStream_t stream)
{
    const float* x   = (const float*)d_in[0];
    const float* enc = (const float*)d_in[1];
    const float* w   = (const float*)d_in[2];
    float* out = (float*)d_out;

    if (ws_size >= 16384) {
        bf16* wfrag = (bf16*)d_ws;
        prep_wfrag<<<1, 256, 0, stream>>>(w, wfrag);
        eegconv_kernel<true><<<NBLK, 256, 0, stream>>>(x, enc, w, wfrag, out);
    } else {
        eegconv_kernel<false><<<NBLK, 256, 0, stream>>>(x, enc, w, nullptr, out);
    }
}